// Round 13
// baseline (38.066 us; speedup 1.0000x reference)
//
#include <hip/hip_runtime.h>
#include <hip/hip_bf16.h>
#include <math.h>

#define GAMMA 0.001f
#define HG2   5.0e-7f   // GAMMA^2 / 2
#define Bn 8192
#define Dk 128
#define NCH 128         // G chunks, 64 rows each; 2 blocks per chunk (output halves)
#define NK3 192         // k_main blocks (64 MFMA + 128 prep)

typedef float f32x4 __attribute__((ext_vector_type(4)));
typedef short bf16x8 __attribute__((ext_vector_type(8)));

// ---------------- ws layout (bytes) ----------------
// Xb    bf16 [8192][128]    @ 0           (2MB)
// Gpb   bf16 [128][16384]   @ 2MB         (4MB)   G partials (bf16)
// Gb    bf16 [16384]        @ 10MB        (32KB)  G final (symmetric)
// Sp    f32  [128][128]     @ 10MB+32KB   (64KB)  column-sum partials
// S     f32  [128]          @ 10MB+192KB
// em    f32  [8192]         @ 11MB                exp(-Wpos)
// pre   f32  [8192]         @ 11MB+32KB
// qpart f32  [2][8192]      @ 11MB+64KB   (64KB)
// counter u32               @ 11MB+128KB  (zeroed by K1 each call)

__device__ inline ushort f2b(float x) {
    union { __hip_bfloat16 h; ushort u; } c;
    c.h = __float2bfloat16(x);
    return c.u;
}
__device__ inline float b2f(ushort u) { return __uint_as_float(((unsigned)u) << 16); }

// K1: G-partials over 64-row chunks, 2 blocks/chunk (output-row halves; twins share
//     an XCD -> dup chunk read is an L2 hit) + fused X->bf16 convert + counter zero
__launch_bounds__(512)
__global__ void k_gpart(const float* __restrict__ X, ushort* __restrict__ Xb,
                        ushort* __restrict__ Gpb, float* __restrict__ Sp,
                        unsigned* __restrict__ counter) {
    int bid = blockIdx.x, tid = threadIdx.x;
    int chunk = bid & (NCH - 1), half = bid >> 7;
    __shared__ float xl[64 * 128];   // 32 KB
    const float4* src = reinterpret_cast<const float4*>(X) + (size_t)chunk * 2048;
    float4* dl = reinterpret_cast<float4*>(xl);
    ushort4* xbo = reinterpret_cast<ushort4*>(Xb) + (size_t)chunk * 2048;
#pragma unroll
    for (int it = 0; it < 4; ++it) {
        int idx = tid + it * 512;
        float4 v = src[idx];
        dl[idx] = v;
        if (half == 0) {   // convert done once per chunk
            ushort4 u;
            u.x = f2b(v.x); u.y = f2b(v.y); u.z = f2b(v.z); u.w = f2b(v.w);
            xbo[idx] = u;
        }
    }
    if (bid == 0 && tid == 0) *counter = 0u;
    __syncthreads();

    // output half: G rows [half*64, half*64+64), all 128 cols; 2x8 tile/thread
    int tr = half * 64 + (tid >> 4) * 2, tc = (tid & 15) * 8;
    float acc[2][8];
#pragma unroll
    for (int i = 0; i < 2; ++i)
#pragma unroll
        for (int j = 0; j < 8; ++j) acc[i][j] = 0.f;
#pragma unroll 4
    for (int k = 0; k < 64; ++k) {
        const float* rowk = &xl[k * 128];
        float a0 = rowk[tr], a1 = rowk[tr + 1];
        float b[8];
        *(float4*)&b[0] = *(const float4*)&rowk[tc];
        *(float4*)&b[4] = *(const float4*)&rowk[tc + 4];
#pragma unroll
        for (int j = 0; j < 8; ++j) {
            acc[0][j] += a0 * b[j];
            acc[1][j] += a1 * b[j];
        }
    }
    ushort* gpo = Gpb + (size_t)chunk * 16384 + tr * 128 + tc;
#pragma unroll
    for (int i = 0; i < 2; ++i) {
        union { ushort s[8]; uint4 v; } pk;
#pragma unroll
        for (int j = 0; j < 8; ++j) pk.s[j] = f2b(acc[i][j]);
        *reinterpret_cast<uint4*>(gpo + i * 128) = pk.v;
    }
    if (half == 0 && tid < 128) {
        float sc = 0.f;
#pragma unroll 8
        for (int k = 0; k < 64; ++k) sc += xl[k * 128 + tid];
        Sp[chunk * 128 + tid] = sc;
    }
}

// K2: G reduce (128 bf16 partials -> Gb bf16) over 128 blocks + S reduce (block 128)
__global__ void k_mid(const ushort* __restrict__ Gpb, ushort* __restrict__ Gb,
                      const float* __restrict__ Sp, float* __restrict__ S) {
    int bid = blockIdx.x, tid = threadIdx.x;
    if (bid < 128) {
        int el = tid & 15, pc = tid >> 4;
        int eg = bid * 16 + el;
        float a8[8];
#pragma unroll
        for (int j = 0; j < 8; ++j) a8[j] = 0.f;
        const ushort* base = Gpb + (size_t)eg * 8;
#pragma unroll
        for (int k = 0; k < 8; ++k) {
            int p = pc + k * 16;
            union { uint4 v; ushort s[8]; } ld;
            ld.v = *reinterpret_cast<const uint4*>(base + (size_t)p * 16384);
#pragma unroll
            for (int j = 0; j < 8; ++j) a8[j] += b2f(ld.s[j]);
        }
        __shared__ float red[16][16][8];   // 8 KB
        __shared__ float red2[128];
#pragma unroll
        for (int j = 0; j < 8; ++j) red[pc][el][j] = a8[j];
        __syncthreads();
        if (tid < 128) {
            int e2 = tid >> 3, j = tid & 7;
            float v = 0.f;
#pragma unroll
            for (int p = 0; p < 16; ++p) v += red[p][e2][j];
            red2[e2 * 8 + j] = v;
        }
        __syncthreads();
        if (tid < 16) {
            union { ushort s[8]; uint4 v; } pk;
#pragma unroll
            for (int j = 0; j < 8; ++j) pk.s[j] = f2b(red2[tid * 8 + j]);
            *reinterpret_cast<uint4*>(Gb + (size_t)(bid * 16 + tid) * 8) = pk.v;
        }
    } else {
        if (tid < 128) {
            float sc = 0.f;
            for (int p = 0; p < NCH; ++p) sc += Sp[p * 128 + tid];
            S[tid] = sc;
        }
    }
}

// pairwise prep (float2-vectorized): rows (2r, 2r+1) share Wpos (adjacent-pair
// labels; exact for <=2 members/label). Generic per-row ballot fallback otherwise.
__device__ inline void prep_pairs(int u, int lane, const float* __restrict__ X,
                                  const int* __restrict__ tgt,
                                  const float* __restrict__ S,
                                  float* __restrict__ em, float* __restrict__ pre) {
    float2 sv = *reinterpret_cast<const float2*>(&S[lane * 2]);
    for (int pr = u; pr < Bn / 2; pr += 512) {
        int i0 = pr * 2, i1 = i0 + 1;
        float2 xv = *reinterpret_cast<const float2*>(&X[(size_t)i0 * 128 + lane * 2]);
        float2 yv = *reinterpret_cast<const float2*>(&X[(size_t)i1 * 128 + lane * 2]);
        float ds0 = xv.x * xv.x + xv.y * xv.y;
        float ds1 = yv.x * yv.x + yv.y * yv.y;
        float dp  = xv.x * yv.x + xv.y * yv.y;
        float sl0 = xv.x * sv.x + xv.y * sv.y;
        float sl1 = yv.x * sv.x + yv.y * sv.y;
        for (int off = 32; off; off >>= 1) {
            ds0 += __shfl_xor(ds0, off);
            ds1 += __shfl_xor(ds1, off);
            dp  += __shfl_xor(dp,  off);
            sl0 += __shfl_xor(sl0, off);
            sl1 += __shfl_xor(sl1, off);
        }
        int t0 = tgt[i0], t1 = tgt[i1];
        if (t0 == t1) {
            if (lane == 0) {
                float wp = GAMMA * dp;
                float e = __expf(-wp);
                float tp = 1.0f + wp + 0.5f * wp * wp;
                float w0 = GAMMA * ds0, w1 = GAMMA * ds1;
                em[i0] = e;
                em[i1] = e;
                pre[i0] = 8192.0f + GAMMA * sl0 - (1.0f + w0 + 0.5f * w0 * w0) - tp;
                pre[i1] = 8192.0f + GAMMA * sl1 - (1.0f + w1 + 0.5f * w1 * w1) - tp;
            }
        } else {
            // generic fallback, per row (never taken for adjacent-pair datasets)
#pragma unroll
            for (int h = 0; h < 2; ++h) {
                int i  = h ? i1 : i0;
                int ti = h ? t1 : t0;
                float a0 = h ? yv.x : xv.x, a1 = h ? yv.y : xv.y;
                float dsi = h ? ds1 : ds0, sli = h ? sl1 : sl0;
                int pos = 0;   // argmax(all-false)==0
                for (int c0 = 0; c0 < Bn; c0 += 64) {
                    int j = c0 + lane;
                    bool m = (tgt[j] == ti) && (j != i);
                    unsigned long long mk = __ballot(m);
                    if (mk) { pos = c0 + __ffsll(mk) - 1; break; }
                }
                float2 pv = *reinterpret_cast<const float2*>(&X[(size_t)pos * 128 + lane * 2]);
                float dpi = a0 * pv.x + a1 * pv.y;
                for (int off = 32; off; off >>= 1) dpi += __shfl_xor(dpi, off);
                if (lane == 0) {
                    float wp = GAMMA * dpi, wi = GAMMA * dsi;
                    em[i] = __expf(-wp);
                    pre[i] = 8192.0f + GAMMA * sli
                             - (1.0f + wi + 0.5f * wi * wi)
                             - (1.0f + wp + 0.5f * wp * wp);
                }
            }
        }
    }
}

// K3: Z = Xb*Gb MFMA (64 blocks) + pairwise prep (128 blocks) + fused finish:
//     last-ticket block computes the full loss (one fence per block, k_fin-validated).
__launch_bounds__(256, 2)
__global__ void k_main(const ushort* __restrict__ Xb, const ushort* __restrict__ Gb,
                       const float* __restrict__ X, const int* __restrict__ tgt,
                       const float* __restrict__ S,
                       float* __restrict__ qpart, float* __restrict__ em,
                       float* __restrict__ pre, unsigned* __restrict__ counter,
                       float* __restrict__ out) {
    int bid = blockIdx.x, tid = threadIdx.x;
    int lane = tid & 63, wid = tid >> 6;
    __shared__ float a4[4];
    __shared__ bool last;
    if (bid < 64) {
        __shared__ ushort sm[32768];   // [0,16384): Xb tile ; [16384,32768): Gb
        const ushort* gA = Xb + (size_t)bid * 16384;
#pragma unroll
        for (int it = 0; it < 8; ++it) {
            int ob = wid * 512 + it * 64;
            int o = ob + lane;
            int src = (o & ~15) | ((o & 15) ^ ((o >> 4) & 7));
            __builtin_amdgcn_global_load_lds(
                (const __attribute__((address_space(1))) void*)(gA + (size_t)src * 8),
                (__attribute__((address_space(3))) void*)(sm + ob * 8), 16, 0, 0);
            __builtin_amdgcn_global_load_lds(
                (const __attribute__((address_space(1))) void*)(Gb + (size_t)src * 8),
                (__attribute__((address_space(3))) void*)(sm + 16384 + ob * 8), 16, 0, 0);
        }
        __syncthreads();
        int wm = wid >> 1, wn = wid & 1, r15 = lane & 15, khalf = lane >> 4;
        const bf16x8* XA = reinterpret_cast<const bf16x8*>(sm);
        const bf16x8* GBL = reinterpret_cast<const bf16x8*>(sm + 16384);
        f32x4 acc[4][4];
#pragma unroll
        for (int m = 0; m < 4; ++m)
#pragma unroll
            for (int n = 0; n < 4; ++n) acc[m][n] = (f32x4){0.f, 0.f, 0.f, 0.f};
#pragma unroll
        for (int ks = 0; ks < 4; ++ks) {
            int u0 = ks * 4 + khalf;
            bf16x8 a[4], b[4];
#pragma unroll
            for (int m = 0; m < 4; ++m) {
                int row = wm * 64 + m * 16 + r15;
                a[m] = XA[row * 16 + (u0 ^ (row & 7))];
            }
#pragma unroll
            for (int n = 0; n < 4; ++n) {
                int row = wn * 64 + n * 16 + r15;
                b[n] = GBL[row * 16 + (u0 ^ (row & 7))];
            }
#pragma unroll
            for (int m = 0; m < 4; ++m)
#pragma unroll
                for (int n = 0; n < 4; ++n)
                    acc[m][n] = __builtin_amdgcn_mfma_f32_16x16x32_bf16(a[m], b[n], acc[m][n], 0, 0, 0);
        }
        float qp[4][4];
#pragma unroll
        for (int m = 0; m < 4; ++m)
#pragma unroll
            for (int r = 0; r < 4; ++r) qp[m][r] = 0.f;
#pragma unroll
        for (int m = 0; m < 4; ++m)
#pragma unroll
            for (int n = 0; n < 4; ++n) {
                int c = wn * 64 + n * 16 + r15;
#pragma unroll
                for (int r = 0; r < 4; ++r) {
                    int il = wm * 64 + m * 16 + khalf * 4 + r;
                    ushort xu = sm[il * 128 + (((c >> 3) ^ (il & 7)) << 3) + (c & 7)];
                    qp[m][r] += acc[m][n][r] * b2f(xu);
                }
            }
#pragma unroll
        for (int m = 0; m < 4; ++m)
#pragma unroll
            for (int r = 0; r < 4; ++r) {
                float v = qp[m][r];
                v += __shfl_xor(v, 1);
                v += __shfl_xor(v, 2);
                v += __shfl_xor(v, 4);
                v += __shfl_xor(v, 8);
                qp[m][r] = v;
            }
        if (r15 == 0) {
#pragma unroll
            for (int m = 0; m < 4; ++m)
#pragma unroll
                for (int r = 0; r < 4; ++r)
                    qpart[(size_t)wn * Bn + bid * 128 + wm * 64 + m * 16 + khalf * 4 + r] = qp[m][r];
        }
    } else {
        prep_pairs((bid - 64) * 4 + wid, lane, X, tgt, S, em, pre);
    }

    // ---- fused finish (k_fin pattern: one fence per block, by tid0 only) ----
    __syncthreads();                      // all this block's stores drained (vmcnt)
    if (tid == 0) {
        __threadfence();                  // release
        unsigned old = atomicAdd(counter, 1u);
        last = (old == NK3 - 1u);
    }
    __syncthreads();
    if (last) {
        __threadfence();                  // acquire on the reading block
        float v = 0.f;
#pragma unroll
        for (int k = 0; k < 32; ++k) {
            int r = tid + k * 256;
            float q = qpart[r] + qpart[Bn + r];
            float s = em[r] * (pre[r] + HG2 * q);
            v += log1pf(s);
        }
        for (int off = 32; off; off >>= 1) v += __shfl_xor(v, off);
        if (lane == 0) a4[wid] = v;
        __syncthreads();
        if (tid == 0) out[0] = (a4[0] + a4[1] + a4[2] + a4[3]) * (1.0f / 8192.0f);
    }
}

extern "C" void kernel_launch(void* const* d_in, const int* in_sizes, int n_in,
                              void* d_out, int out_size, void* d_ws, size_t ws_size,
                              hipStream_t stream) {
    const float* X  = (const float*)d_in[0];
    const int* tgt  = (const int*)d_in[1];
    float* out      = (float*)d_out;
    char* ws        = (char*)d_ws;

    const size_t MB = 1024 * 1024;
    ushort* Xb        = (ushort*)ws;
    ushort* Gpb       = (ushort*)(ws + 2 * MB);
    ushort* Gb        = (ushort*)(ws + 10 * MB);
    float* Sp         = (float*)(ws + 10 * MB + 32 * 1024);
    float* S          = (float*)(ws + 10 * MB + 192 * 1024);
    float* em         = (float*)(ws + 11 * MB);
    float* pre        = (float*)(ws + 11 * MB + 32 * 1024);
    float* qpart      = (float*)(ws + 11 * MB + 64 * 1024);
    unsigned* counter = (unsigned*)(ws + 11 * MB + 128 * 1024);

    k_gpart<<<2 * NCH, 512, 0, stream>>>(X, Xb, Gpb, Sp, counter);
    k_mid<<<129, 256, 0, stream>>>(Gpb, Gb, Sp, S);
    k_main<<<NK3, 256, 0, stream>>>(Xb, Gb, X, tgt, S, qpart, em, pre, counter, out);
}

// Round 14
// 28.245 us; speedup vs baseline: 1.3477x; 1.3477x over previous
//
#include <hip/hip_runtime.h>
#include <hip/hip_bf16.h>
#include <math.h>

#define GAMMA 0.001f
#define HG2   5.0e-7f   // GAMMA^2 / 2
#define Bn 8192
#define Dk 128
#define NCH 128         // G chunks, 64 rows each; 2 blocks per chunk (output halves)

typedef float f32x4 __attribute__((ext_vector_type(4)));
typedef short bf16x8 __attribute__((ext_vector_type(8)));

// ---------------- ws layout (bytes) ----------------
// Xb    bf16 [8192][128]    @ 0           (2MB)
// Gpb   bf16 [128][16384]   @ 2MB         (4MB)   G partials (bf16)
// Gb    bf16 [16384]        @ 10MB        (32KB)  G final (symmetric)
// Sp    f32  [128][128]     @ 10MB+32KB   (64KB)  column-sum partials
// S     f32  [128]          @ 10MB+192KB
// em    f32  [8192]         @ 11MB                exp(-Wpos)
// pre   f32  [8192]         @ 11MB+32KB
// qpart f32  [2][8192]      @ 11MB+64KB   (64KB)
// blocksum f32[16]          @ 11MB+128KB ; counter u32 @ +256B

__device__ inline ushort f2b(float x) {
    union { __hip_bfloat16 h; ushort u; } c;
    c.h = __float2bfloat16(x);
    return c.u;
}
__device__ inline float b2f(ushort u) { return __uint_as_float(((unsigned)u) << 16); }

// K1: G-partials over 64-row chunks, 2 blocks/chunk (output-row halves; twins share
//     an XCD -> dup chunk read is an L2 hit) + fused X->bf16 convert + counter zero
__launch_bounds__(512)
__global__ void k_gpart(const float* __restrict__ X, ushort* __restrict__ Xb,
                        ushort* __restrict__ Gpb, float* __restrict__ Sp,
                        unsigned* __restrict__ counter) {
    int bid = blockIdx.x, tid = threadIdx.x;
    int chunk = bid & (NCH - 1), half = bid >> 7;
    __shared__ float xl[64 * 128];   // 32 KB
    const float4* src = reinterpret_cast<const float4*>(X) + (size_t)chunk * 2048;
    float4* dl = reinterpret_cast<float4*>(xl);
    ushort4* xbo = reinterpret_cast<ushort4*>(Xb) + (size_t)chunk * 2048;
#pragma unroll
    for (int it = 0; it < 4; ++it) {
        int idx = tid + it * 512;
        float4 v = src[idx];
        dl[idx] = v;
        if (half == 0) {   // convert done once per chunk
            ushort4 u;
            u.x = f2b(v.x); u.y = f2b(v.y); u.z = f2b(v.z); u.w = f2b(v.w);
            xbo[idx] = u;
        }
    }
    if (bid == 0 && tid == 0) *counter = 0u;
    __syncthreads();

    // output half: G rows [half*64, half*64+64), all 128 cols; 2x8 tile/thread
    int tr = half * 64 + (tid >> 4) * 2, tc = (tid & 15) * 8;
    float acc[2][8];
#pragma unroll
    for (int i = 0; i < 2; ++i)
#pragma unroll
        for (int j = 0; j < 8; ++j) acc[i][j] = 0.f;
#pragma unroll 4
    for (int k = 0; k < 64; ++k) {
        const float* rowk = &xl[k * 128];
        float a0 = rowk[tr], a1 = rowk[tr + 1];
        float b[8];
        *(float4*)&b[0] = *(const float4*)&rowk[tc];
        *(float4*)&b[4] = *(const float4*)&rowk[tc + 4];
#pragma unroll
        for (int j = 0; j < 8; ++j) {
            acc[0][j] += a0 * b[j];
            acc[1][j] += a1 * b[j];
        }
    }
    ushort* gpo = Gpb + (size_t)chunk * 16384 + tr * 128 + tc;
#pragma unroll
    for (int i = 0; i < 2; ++i) {
        union { ushort s[8]; uint4 v; } pk;
#pragma unroll
        for (int j = 0; j < 8; ++j) pk.s[j] = f2b(acc[i][j]);
        *reinterpret_cast<uint4*>(gpo + i * 128) = pk.v;
    }
    if (half == 0 && tid < 128) {
        float sc = 0.f;
#pragma unroll 8
        for (int k = 0; k < 64; ++k) sc += xl[k * 128 + tid];
        Sp[chunk * 128 + tid] = sc;
    }
}

// K2: G reduce (128 bf16 partials -> Gb bf16) over 128 blocks + S reduce (block 128)
__global__ void k_mid(const ushort* __restrict__ Gpb, ushort* __restrict__ Gb,
                      const float* __restrict__ Sp, float* __restrict__ S) {
    int bid = blockIdx.x, tid = threadIdx.x;
    if (bid < 128) {
        // block b: eg in [b*16, b*16+16); pc = tid>>4 covers 8 partials each
        int el = tid & 15, pc = tid >> 4;
        int eg = bid * 16 + el;
        float a8[8];
#pragma unroll
        for (int j = 0; j < 8; ++j) a8[j] = 0.f;
        const ushort* base = Gpb + (size_t)eg * 8;
#pragma unroll
        for (int k = 0; k < 8; ++k) {
            int p = pc + k * 16;
            union { uint4 v; ushort s[8]; } ld;
            ld.v = *reinterpret_cast<const uint4*>(base + (size_t)p * 16384);
#pragma unroll
            for (int j = 0; j < 8; ++j) a8[j] += b2f(ld.s[j]);
        }
        __shared__ float red[16][16][8];   // 8 KB
        __shared__ float red2[128];
#pragma unroll
        for (int j = 0; j < 8; ++j) red[pc][el][j] = a8[j];
        __syncthreads();
        if (tid < 128) {
            int e2 = tid >> 3, j = tid & 7;
            float v = 0.f;
#pragma unroll
            for (int p = 0; p < 16; ++p) v += red[p][e2][j];
            red2[e2 * 8 + j] = v;
        }
        __syncthreads();
        if (tid < 16) {
            union { ushort s[8]; uint4 v; } pk;
#pragma unroll
            for (int j = 0; j < 8; ++j) pk.s[j] = f2b(red2[tid * 8 + j]);
            *reinterpret_cast<uint4*>(Gb + (size_t)(bid * 16 + tid) * 8) = pk.v;
        }
    } else {
        if (tid < 128) {
            float sc = 0.f;
            for (int p = 0; p < NCH; ++p) sc += Sp[p * 128 + tid];
            S[tid] = sc;
        }
    }
}

// pairwise prep (float2-vectorized): rows (2r, 2r+1) share Wpos (adjacent-pair
// labels; exact for <=2 members/label). Generic per-row ballot fallback otherwise.
__device__ inline void prep_pairs(int u, int lane, const float* __restrict__ X,
                                  const int* __restrict__ tgt,
                                  const float* __restrict__ S,
                                  float* __restrict__ em, float* __restrict__ pre) {
    float2 sv = *reinterpret_cast<const float2*>(&S[lane * 2]);
    for (int pr = u; pr < Bn / 2; pr += 512) {
        int i0 = pr * 2, i1 = i0 + 1;
        float2 xv = *reinterpret_cast<const float2*>(&X[(size_t)i0 * 128 + lane * 2]);
        float2 yv = *reinterpret_cast<const float2*>(&X[(size_t)i1 * 128 + lane * 2]);
        float ds0 = xv.x * xv.x + xv.y * xv.y;
        float ds1 = yv.x * yv.x + yv.y * yv.y;
        float dp  = xv.x * yv.x + xv.y * yv.y;
        float sl0 = xv.x * sv.x + xv.y * sv.y;
        float sl1 = yv.x * sv.x + yv.y * sv.y;
        for (int off = 32; off; off >>= 1) {
            ds0 += __shfl_xor(ds0, off);
            ds1 += __shfl_xor(ds1, off);
            dp  += __shfl_xor(dp,  off);
            sl0 += __shfl_xor(sl0, off);
            sl1 += __shfl_xor(sl1, off);
        }
        int t0 = tgt[i0], t1 = tgt[i1];
        if (t0 == t1) {
            if (lane == 0) {
                float wp = GAMMA * dp;
                float e = __expf(-wp);
                float tp = 1.0f + wp + 0.5f * wp * wp;
                float w0 = GAMMA * ds0, w1 = GAMMA * ds1;
                em[i0] = e;
                em[i1] = e;
                pre[i0] = 8192.0f + GAMMA * sl0 - (1.0f + w0 + 0.5f * w0 * w0) - tp;
                pre[i1] = 8192.0f + GAMMA * sl1 - (1.0f + w1 + 0.5f * w1 * w1) - tp;
            }
        } else {
            // generic fallback, per row (never taken for adjacent-pair datasets)
#pragma unroll
            for (int h = 0; h < 2; ++h) {
                int i  = h ? i1 : i0;
                int ti = h ? t1 : t0;
                float a0 = h ? yv.x : xv.x, a1 = h ? yv.y : xv.y;
                float dsi = h ? ds1 : ds0, sli = h ? sl1 : sl0;
                int pos = 0;   // argmax(all-false)==0
                for (int c0 = 0; c0 < Bn; c0 += 64) {
                    int j = c0 + lane;
                    bool m = (tgt[j] == ti) && (j != i);
                    unsigned long long mk = __ballot(m);
                    if (mk) { pos = c0 + __ffsll(mk) - 1; break; }
                }
                float2 pv = *reinterpret_cast<const float2*>(&X[(size_t)pos * 128 + lane * 2]);
                float dpi = a0 * pv.x + a1 * pv.y;
                for (int off = 32; off; off >>= 1) dpi += __shfl_xor(dpi, off);
                if (lane == 0) {
                    float wp = GAMMA * dpi, wi = GAMMA * dsi;
                    em[i] = __expf(-wp);
                    pre[i] = 8192.0f + GAMMA * sli
                             - (1.0f + wi + 0.5f * wi * wi)
                             - (1.0f + wp + 0.5f * wp * wp);
                }
            }
        }
    }
}

// K3: Z = Xb*Gb MFMA (64 blocks) with fused quad epilogue + pairwise prep (128 blocks)
__launch_bounds__(256, 2)
__global__ void k_main(const ushort* __restrict__ Xb, const ushort* __restrict__ Gb,
                       const float* __restrict__ X, const int* __restrict__ tgt,
                       const float* __restrict__ S,
                       float* __restrict__ qpart, float* __restrict__ em,
                       float* __restrict__ pre) {
    int bid = blockIdx.x, tid = threadIdx.x;
    int lane = tid & 63, wid = tid >> 6;
    if (bid < 64) {
        __shared__ ushort sm[32768];   // [0,16384): Xb tile ; [16384,32768): Gb
        const ushort* gA = Xb + (size_t)bid * 16384;
#pragma unroll
        for (int it = 0; it < 8; ++it) {
            int ob = wid * 512 + it * 64;
            int o = ob + lane;
            int src = (o & ~15) | ((o & 15) ^ ((o >> 4) & 7));
            __builtin_amdgcn_global_load_lds(
                (const __attribute__((address_space(1))) void*)(gA + (size_t)src * 8),
                (__attribute__((address_space(3))) void*)(sm + ob * 8), 16, 0, 0);
            __builtin_amdgcn_global_load_lds(
                (const __attribute__((address_space(1))) void*)(Gb + (size_t)src * 8),
                (__attribute__((address_space(3))) void*)(sm + 16384 + ob * 8), 16, 0, 0);
        }
        __syncthreads();
        int wm = wid >> 1, wn = wid & 1, r15 = lane & 15, khalf = lane >> 4;
        const bf16x8* XA = reinterpret_cast<const bf16x8*>(sm);
        const bf16x8* GBL = reinterpret_cast<const bf16x8*>(sm + 16384);
        f32x4 acc[4][4];
#pragma unroll
        for (int m = 0; m < 4; ++m)
#pragma unroll
            for (int n = 0; n < 4; ++n) acc[m][n] = (f32x4){0.f, 0.f, 0.f, 0.f};
#pragma unroll
        for (int ks = 0; ks < 4; ++ks) {
            int u0 = ks * 4 + khalf;
            bf16x8 a[4], b[4];
#pragma unroll
            for (int m = 0; m < 4; ++m) {
                int row = wm * 64 + m * 16 + r15;
                a[m] = XA[row * 16 + (u0 ^ (row & 7))];
            }
#pragma unroll
            for (int n = 0; n < 4; ++n) {
                int row = wn * 64 + n * 16 + r15;
                b[n] = GBL[row * 16 + (u0 ^ (row & 7))];
            }
#pragma unroll
            for (int m = 0; m < 4; ++m)
#pragma unroll
                for (int n = 0; n < 4; ++n)
                    acc[m][n] = __builtin_amdgcn_mfma_f32_16x16x32_bf16(a[m], b[n], acc[m][n], 0, 0, 0);
        }
        float qp[4][4];
#pragma unroll
        for (int m = 0; m < 4; ++m)
#pragma unroll
            for (int r = 0; r < 4; ++r) qp[m][r] = 0.f;
#pragma unroll
        for (int m = 0; m < 4; ++m)
#pragma unroll
            for (int n = 0; n < 4; ++n) {
                int c = wn * 64 + n * 16 + r15;
#pragma unroll
                for (int r = 0; r < 4; ++r) {
                    int il = wm * 64 + m * 16 + khalf * 4 + r;
                    ushort xu = sm[il * 128 + (((c >> 3) ^ (il & 7)) << 3) + (c & 7)];
                    qp[m][r] += acc[m][n][r] * b2f(xu);
                }
            }
#pragma unroll
        for (int m = 0; m < 4; ++m)
#pragma unroll
            for (int r = 0; r < 4; ++r) {
                float v = qp[m][r];
                v += __shfl_xor(v, 1);
                v += __shfl_xor(v, 2);
                v += __shfl_xor(v, 4);
                v += __shfl_xor(v, 8);
                qp[m][r] = v;
            }
        if (r15 == 0) {
#pragma unroll
            for (int m = 0; m < 4; ++m)
#pragma unroll
                for (int r = 0; r < 4; ++r)
                    qpart[(size_t)wn * Bn + bid * 128 + wm * 64 + m * 16 + khalf * 4 + r] = qp[m][r];
        }
    } else {
        prep_pairs((bid - 64) * 4 + wid, lane, X, tgt, S, em, pre);
    }
}

// K4: s_i = em*(pre + HG2*quad); loss = mean(log1p(s)); grid reduce via counter
__global__ void k_fin(const float* __restrict__ qpart, const float* __restrict__ em,
                      const float* __restrict__ pre, float* __restrict__ blocksum,
                      unsigned* __restrict__ counter, float* __restrict__ out) {
    int bid = blockIdx.x, tid = threadIdx.x;
    float v = 0.f;
#pragma unroll
    for (int h = 0; h < 2; ++h) {
        int r = bid * 512 + h * 256 + tid;
        float q = qpart[r] + qpart[Bn + r];
        float s = em[r] * (pre[r] + HG2 * q);
        v += log1pf(s);
    }
    for (int off = 32; off; off >>= 1) v += __shfl_xor(v, off);
    __shared__ float a4[4];
    __shared__ bool last;
    int lane = tid & 63, wid = tid >> 6;
    if (lane == 0) a4[wid] = v;
    __syncthreads();
    if (tid == 0) {
        blocksum[bid] = a4[0] + a4[1] + a4[2] + a4[3];
        __threadfence();
        unsigned old = atomicAdd(counter, 1u);
        last = (old == 15u);
    }
    __syncthreads();
    if (last && tid < 16) {
        __threadfence();
        float x = ((volatile float*)blocksum)[tid];
        x += __shfl_xor(x, 1);
        x += __shfl_xor(x, 2);
        x += __shfl_xor(x, 4);
        x += __shfl_xor(x, 8);
        if (tid == 0) out[0] = x * (1.0f / 8192.0f);
    }
}

extern "C" void kernel_launch(void* const* d_in, const int* in_sizes, int n_in,
                              void* d_out, int out_size, void* d_ws, size_t ws_size,
                              hipStream_t stream) {
    const float* X  = (const float*)d_in[0];
    const int* tgt  = (const int*)d_in[1];
    float* out      = (float*)d_out;
    char* ws        = (char*)d_ws;

    const size_t MB = 1024 * 1024;
    ushort* Xb        = (ushort*)ws;
    ushort* Gpb       = (ushort*)(ws + 2 * MB);
    ushort* Gb        = (ushort*)(ws + 10 * MB);
    float* Sp         = (float*)(ws + 10 * MB + 32 * 1024);
    float* S          = (float*)(ws + 10 * MB + 192 * 1024);
    float* em         = (float*)(ws + 11 * MB);
    float* pre        = (float*)(ws + 11 * MB + 32 * 1024);
    float* qpart      = (float*)(ws + 11 * MB + 64 * 1024);
    float* blocksum   = (float*)(ws + 11 * MB + 128 * 1024);
    unsigned* counter = (unsigned*)(ws + 11 * MB + 128 * 1024 + 256);

    k_gpart<<<2 * NCH, 512, 0, stream>>>(X, Xb, Gpb, Sp, counter);
    k_mid<<<129, 256, 0, stream>>>(Gpb, Gb, Sp, S);
    k_main<<<192, 256, 0, stream>>>(Xb, Gb, X, tgt, S, qpart, em, pre);
    k_fin<<<16, 256, 0, stream>>>(qpart, em, pre, blocksum, counter, out);
}